// Round 14
// baseline (53.839 us; speedup 1.0000x reference)
//
#include <hip/hip_runtime.h>
#include <hip/hip_bf16.h>
#include <math.h>

// Problem constants (fixed by setup_inputs)
#define BB 2
#define NN 4096
#define MM 4096
#define DD 64

#define NSPLIT 8
#define MRANGE (MM / NSPLIT)   // 512 m per block
#define BMT 64                 // m per M-step
#define NSTEP (MRANGE / BMT)   // 8
#define BLK_N 128              // n rows per block (4 waves x 32)
#define NBLK_B (NN / BLK_N)    // 32 n-blocks per batch

typedef __attribute__((ext_vector_type(8))) short bf16x8;   // 8 bf16 (4 VGPRs)
typedef __attribute__((ext_vector_type(4))) float f32x4;

#define FEAT_BLOCKS ((BB * (NN + MM)) / 4)    // 4096
#define COORD_BLOCKS ((BB * (NN + MM)) / 256) // 64

// ---------------------------------------------------------------------------
// Fused prep: (a) L2-normalize features; source rows -> [hi|lo] bf16 split
//   (fs2, 128/row); target rows -> hi-only DENSE array (fth, 64/row, 1 MB).
// (b) coordinate float4 tables {x,y,z,|c|^2}; (c) zero tile counters.
// ---------------------------------------------------------------------------
__global__ __launch_bounds__(256) void prep_all(const float* __restrict__ fs,
                                                const float* __restrict__ ft,
                                                const float* __restrict__ cs,
                                                const float* __restrict__ ct,
                                                unsigned short* __restrict__ fs2,
                                                unsigned short* __restrict__ fth,
                                                float4* __restrict__ cs4,
                                                float4* __restrict__ ct4,
                                                int* __restrict__ cnt) {
    int bid = blockIdx.x;
    if (bid < FEAT_BLOCKS) {
        int row  = bid * 4 + (threadIdx.x >> 6);   // 4 waves per block
        int lane = threadIdx.x & 63;
        if (row < BB * NN) {
            float x = fs[(size_t)row * DD + lane];
            float s = x * x;
            #pragma unroll
            for (int o = 32; o > 0; o >>= 1) s += __shfl_xor(s, o, 64);
            float xn = x / sqrtf(s);
            __hip_bfloat16 h = __float2bfloat16(xn);
            float hf = __bfloat162float(h);
            __hip_bfloat16 l = __float2bfloat16(xn - hf);
            fs2[(size_t)row * 128 + lane]      = *(unsigned short*)&h;
            fs2[(size_t)row * 128 + 64 + lane] = *(unsigned short*)&l;
        } else {
            int r = row - BB * NN;
            float x = ft[(size_t)r * DD + lane];
            float s = x * x;
            #pragma unroll
            for (int o = 32; o > 0; o >>= 1) s += __shfl_xor(s, o, 64);
            float xn = x / sqrtf(s);
            __hip_bfloat16 h = __float2bfloat16(xn);
            fth[(size_t)r * 64 + lane] = *(unsigned short*)&h;
        }
    } else {
        int cb = bid - FEAT_BLOCKS;
        if (cb == 0 && threadIdx.x < BB * NBLK_B) cnt[threadIdx.x] = 0;
        int i = cb * 256 + threadIdx.x;               // over BB*(NN+MM) pts
        const float* c; float4* d;
        if (i < BB * NN) { c = cs + (size_t)i * 3; d = cs4 + i; }
        else { int r = i - BB * NN; c = ct + (size_t)r * 3; d = ct4 + r; }
        float x = c[0], y = c[1], z = c[2];
        *d = make_float4(x, y, z, x * x + y * y + z * z);
    }
}

// ---------------------------------------------------------------------------
// Main: MFMA pair kernel — R11 dataflow (best measured: 36.2 us) with two
// isolated cuts:
//  (1) ONE barrier/step: order is wait vmcnt(0) -> barrier -> cv4 prefetch ->
//      STAGE(next) -> compute. Readers of buffer cur^1 (compute step s-1) all
//      passed barrier(s) before any wave writes it -> WAR-safe. cv4 is issued
//      BEFORE STAGE so the compiler's cv4 waits don't drain the in-flight
//      stage (FIFO vmcnt).
//  (2) fused finalize tail (atomic counter per n-tile; fence/atomic sequence
//      validated in R5, absmax 0.0) -> no finish kernel, one less launch.
// Numerics identical to R11 (absmax 0.0): dot = (hi_s+lo_s).hi_t; mask
// st3 > thr[i] + 0.5*cv.w <=> d2 < 100.
// launch_bounds (256,2): NEVER cap below natural VGPR need (R6/R12 spills).
// ---------------------------------------------------------------------------
__global__ __launch_bounds__(256, 2) void flow_mfma(
    const unsigned short* __restrict__ fs2, const unsigned short* __restrict__ fth,
    const float4* __restrict__ cs4, const float4* __restrict__ ct4,
    const float* __restrict__ eps, float4* __restrict__ part,
    int* __restrict__ cnt, float* __restrict__ out) {

    __shared__ unsigned short ftl[2][BMT * 64];   // 2 x 8 KB (hi half only)
    __shared__ int last_flag;

    const int t    = threadIdx.x;
    const int lane = t & 63;
    const int w    = t >> 6;        // wave 0..3
    const int l15  = lane & 15;
    const int g    = lane >> 4;     // 16-lane group 0..3

    const int bidx  = blockIdx.x;   // 0 .. BB*NBLK_B-1 (64)
    const int split = blockIdx.y;   // 0 .. NSPLIT-1
    const int b   = bidx >> 5;      // NBLK_B = 32
    const int n0  = (bidx & 31) * BLK_N;
    const int n0w = n0 + w * 32;
    const int m0s = split * MRANGE;

    // w = exp(-(2-2*dot)/tau) = exp2((dot-1)*k2)
    const float k2 = 2.0f * 1.44269504f / (__expf(eps[0]) + 0.03f);

    // Hoist A-fragments: wave's 32 fs2 rows as two 16-row tiles, K=128 in 4
    // chunks of 32 (chunks 0,1 = hi dims; 2,3 = lo dims).
    // A layout (16x16x32): row = lane&15, k-chunk slot = lane>>4.
    bf16x8 aA[4], aB[4];
    {
        const unsigned short* arowA = fs2 + ((size_t)b * NN + n0w + l15) * 128;
        const unsigned short* arowB = arowA + (size_t)16 * 128;
        #pragma unroll
        for (int c = 0; c < 4; ++c) {
            aA[c] = *(const bf16x8*)(arowA + c * 32 + g * 8);
            aB[c] = *(const bf16x8*)(arowB + c * 32 + g * 8);
        }
    }
    // Hoist cs: n = n0w + 16*h + 4g + r -> index h*4+r.
    // thr = 0.5*(|cs|^2 - 100): mask d2<100 <=> st3 > thr + 0.5*|ct|^2
    float sx[8], sy[8], sz[8], thr[8];
    #pragma unroll
    for (int h = 0; h < 2; ++h)
        #pragma unroll
        for (int r = 0; r < 4; ++r) {
            float4 v = cs4[(size_t)b * NN + n0w + 16 * h + 4 * g + r];
            sx[h * 4 + r] = v.x; sy[h * 4 + r] = v.y;
            sz[h * 4 + r] = v.z; thr[h * 4 + r] = 0.5f * (v.w - 100.0f);
        }

    float accx[8], accy[8], accz[8], accw[8];
    #pragma unroll
    for (int i = 0; i < 8; ++i) { accx[i] = 0.f; accy[i] = 0.f; accz[i] = 0.f; accw[i] = 0.f; }

    const unsigned short* fthb = fth + (size_t)b * MM * 64;
    const float4* ctb = ct4 + (size_t)b * MM;

    // stage: 2 global_load_lds(16B) per wave (64 rows x 128B = 512 granules);
    // LDS dest linear, global source pre-swizzled (q ^ (m&7)) so the swizzled
    // READ is conflict-free (rule 21; measured 0 conflicts since R8).
    auto STAGE = [&](int buf, int step) {
        const int m0 = m0s + step * BMT;
        #pragma unroll
        for (int i = 0; i < 2; ++i) {
            int idx = w * 128 + i * 64 + lane;           // 16B granule 0..511
            int m   = idx >> 3;                          // row 0..63
            int q   = idx & 7;                           // granule within row
            int sg  = q ^ (m & 7);                       // inverse swizzle on src
            const unsigned short* src = fthb + (size_t)(m0 + m) * 64 + sg * 8;
            unsigned short* dst = (unsigned short*)&ftl[buf][(size_t)idx * 8];
            __builtin_amdgcn_global_load_lds(
                (const __attribute__((address_space(1))) void*)src,
                (__attribute__((address_space(3))) void*)dst, 16, 0, 0);
        }
    };

    int cur = 0;
    STAGE(0, 0);

    for (int step = 0; step < NSTEP; ++step) {
        asm volatile("s_waitcnt vmcnt(0)" ::: "memory");   // STAGE(step) landed
        __builtin_amdgcn_s_barrier();   // all waves done reading buf cur^1
        asm volatile("" ::: "memory");

        const int m0 = m0s + step * BMT;
        // cv4 prefetch FIRST (so compiler's cv waits keep the stage in flight)
        float4 cv4[4];
        #pragma unroll
        for (int st = 0; st < 4; ++st)
            cv4[st] = ctb[m0 + st * 16 + l15];
        // then issue next step's staging into the just-freed buffer
        if (step + 1 < NSTEP) STAGE(cur ^ 1, step + 1);

        #pragma unroll
        for (int st = 0; st < 4; ++st) {
            const int mloc = st * 16 + l15;              // this lane's m column
            const float4 cv = cv4[st];

            // B-frags (hi chunks): col = lane&15 = m, granule swizzled by row
            bf16x8 bf0 = *(const bf16x8*)&ftl[cur][(size_t)mloc * 64 + (((0 * 4 + g) ^ (mloc & 7)) * 8)];
            bf16x8 bf1 = *(const bf16x8*)&ftl[cur][(size_t)mloc * 64 + (((1 * 4 + g) ^ (mloc & 7)) * 8)];

            f32x4 CA = {0.f, 0.f, 0.f, 0.f};
            f32x4 CB = {0.f, 0.f, 0.f, 0.f};
            // hi_s.hi_t
            CA = __builtin_amdgcn_mfma_f32_16x16x32_bf16(aA[0], bf0, CA, 0, 0, 0);
            CB = __builtin_amdgcn_mfma_f32_16x16x32_bf16(aB[0], bf0, CB, 0, 0, 0);
            CA = __builtin_amdgcn_mfma_f32_16x16x32_bf16(aA[1], bf1, CA, 0, 0, 0);
            CB = __builtin_amdgcn_mfma_f32_16x16x32_bf16(aB[1], bf1, CB, 0, 0, 0);
            // lo_s.hi_t
            CA = __builtin_amdgcn_mfma_f32_16x16x32_bf16(aA[2], bf0, CA, 0, 0, 0);
            CB = __builtin_amdgcn_mfma_f32_16x16x32_bf16(aB[2], bf0, CB, 0, 0, 0);
            CA = __builtin_amdgcn_mfma_f32_16x16x32_bf16(aA[3], bf1, CA, 0, 0, 0);
            CB = __builtin_amdgcn_mfma_f32_16x16x32_bf16(aB[3], bf1, CB, 0, 0, 0);

            const float thrc = 0.5f * cv.w;
            #pragma unroll
            for (int h = 0; h < 2; ++h) {
                #pragma unroll
                for (int r = 0; r < 4; ++r) {
                    const int i = h * 4 + r;
                    const float dotv = (h == 0) ? CA[r] : CB[r];
                    float st3 = fmaf(sx[i], cv.x, fmaf(sy[i], cv.y, sz[i] * cv.z));
                    float arg = fmaf(dotv, k2, -k2);
                    float argm = (st3 > thr[i] + thrc) ? arg : -500.0f;  // exp2(-500)=0
                    float wgt = exp2f(argm);
                    accx[i] = fmaf(wgt, cv.x, accx[i]);
                    accy[i] = fmaf(wgt, cv.y, accy[i]);
                    accz[i] = fmaf(wgt, cv.z, accz[i]);
                    accw[i] += wgt;
                }
            }
        }
        cur ^= 1;
    }

    // reduce across the 16 lanes of each group (same n set, different m)
    #pragma unroll
    for (int i = 0; i < 8; ++i) {
        #pragma unroll
        for (int o = 1; o < 16; o <<= 1) {
            accx[i] += __shfl_xor(accx[i], o, 16);
            accy[i] += __shfl_xor(accy[i], o, 16);
            accz[i] += __shfl_xor(accz[i], o, 16);
            accw[i] += __shfl_xor(accw[i], o, 16);
        }
    }
    if (l15 == 0) {
        #pragma unroll
        for (int h = 0; h < 2; ++h) {
            #pragma unroll
            for (int r = 0; r < 4; ++r) {
                int n = n0w + 16 * h + 4 * g + r;
                part[((size_t)split * BB + b) * NN + n] =
                    make_float4(accx[h * 4 + r], accy[h * 4 + r],
                                accz[h * 4 + r], accw[h * 4 + r]);
            }
        }
    }

    // -------- fused finalize: last split-block for this n-tile combines ----
    // (sequence validated in R5: syncthreads drains stores; threadfence +
    //  device-scope atomic publish; reader threadfence invalidates L2)
    __syncthreads();
    if (t == 0) {
        __threadfence();
        int old = atomicAdd(&cnt[bidx], 1);
        last_flag = (old == NSPLIT - 1);
    }
    __syncthreads();
    if (last_flag) {
        __threadfence();
        if (t < BLK_N) {
            int n = n0 + t;
            float x = 0.f, y = 0.f, z = 0.f, ww = 0.f;
            #pragma unroll
            for (int s = 0; s < NSPLIT; ++s) {
                const float4 v = part[((size_t)s * BB + b) * NN + n];
                x += v.x; y += v.y; z += v.z; ww += v.w;
            }
            const float den = ww + 1e-8f;
            const float4 sc = cs4[(size_t)b * NN + n];
            size_t o = ((size_t)b * NN + n) * 3;
            out[o + 0] = x / den - sc.x;
            out[o + 1] = y / den - sc.y;
            out[o + 2] = z / den - sc.z;
        }
    }
}

extern "C" void kernel_launch(void* const* d_in, const int* in_sizes, int n_in,
                              void* d_out, int out_size, void* d_ws, size_t ws_size,
                              hipStream_t stream) {
    const float* feat_s = (const float*)d_in[0];
    const float* feat_t = (const float*)d_in[1];
    const float* coor_s = (const float*)d_in[2];
    const float* coor_t = (const float*)d_in[3];
    const float* eps    = (const float*)d_in[4];
    float* out = (float*)d_out;

    // workspace layout: fs2 2MB | fth 1MB | cs4 128KB | ct4 128KB | part 1MB | cnt
    unsigned short* fs2 = (unsigned short*)d_ws;
    unsigned short* fth = fs2 + (size_t)BB * NN * 128;
    float4* cs4  = (float4*)(fth + (size_t)BB * MM * 64);
    float4* ct4  = cs4 + (size_t)BB * NN;
    float4* part = ct4 + (size_t)BB * MM;
    int*    cnt  = (int*)(part + (size_t)NSPLIT * BB * NN);

    prep_all<<<FEAT_BLOCKS + COORD_BLOCKS, 256, 0, stream>>>(
        feat_s, feat_t, coor_s, coor_t, fs2, fth, cs4, ct4, cnt);

    flow_mfma<<<dim3(BB * NBLK_B, NSPLIT), 256, 0, stream>>>(
        fs2, fth, cs4, ct4, eps, part, cnt, out);
}

// Round 15
// 36.199 us; speedup vs baseline: 1.4873x; 1.4873x over previous
//
#include <hip/hip_runtime.h>
#include <hip/hip_bf16.h>
#include <math.h>

// Problem constants (fixed by setup_inputs)
#define BB 2
#define NN 4096
#define MM 4096
#define DD 64

#define NSPLIT 8
#define MRANGE (MM / NSPLIT)   // 512 m per block
#define BMT 64                 // m per M-step
#define NSTEP (MRANGE / BMT)   // 8
#define BLK_N 128              // n rows per block (4 waves x 32)
#define NBLK_B (NN / BLK_N)    // 32 n-blocks per batch

typedef __attribute__((ext_vector_type(8))) short bf16x8;   // 8 bf16 (4 VGPRs)
typedef __attribute__((ext_vector_type(4))) float f32x4;

#define FEAT_BLOCKS ((BB * (NN + MM)) / 4)    // 4096
#define COORD_BLOCKS ((BB * (NN + MM)) / 256) // 64

// ---------------------------------------------------------------------------
// Fused prep: (a) L2-normalize features; source rows -> [hi|lo] bf16 split
//   (fs2, 128/row); target rows -> hi-only DENSE array (fth, 64/row, 1 MB).
// (b) coordinate float4 tables {x,y,z,|c|^2}.
// ---------------------------------------------------------------------------
__global__ __launch_bounds__(256) void prep_all(const float* __restrict__ fs,
                                                const float* __restrict__ ft,
                                                const float* __restrict__ cs,
                                                const float* __restrict__ ct,
                                                unsigned short* __restrict__ fs2,
                                                unsigned short* __restrict__ fth,
                                                float4* __restrict__ cs4,
                                                float4* __restrict__ ct4) {
    int bid = blockIdx.x;
    if (bid < FEAT_BLOCKS) {
        int row  = bid * 4 + (threadIdx.x >> 6);   // 4 waves per block
        int lane = threadIdx.x & 63;
        if (row < BB * NN) {
            float x = fs[(size_t)row * DD + lane];
            float s = x * x;
            #pragma unroll
            for (int o = 32; o > 0; o >>= 1) s += __shfl_xor(s, o, 64);
            float xn = x / sqrtf(s);
            __hip_bfloat16 h = __float2bfloat16(xn);
            float hf = __bfloat162float(h);
            __hip_bfloat16 l = __float2bfloat16(xn - hf);
            fs2[(size_t)row * 128 + lane]      = *(unsigned short*)&h;
            fs2[(size_t)row * 128 + 64 + lane] = *(unsigned short*)&l;
        } else {
            int r = row - BB * NN;
            float x = ft[(size_t)r * DD + lane];
            float s = x * x;
            #pragma unroll
            for (int o = 32; o > 0; o >>= 1) s += __shfl_xor(s, o, 64);
            float xn = x / sqrtf(s);
            __hip_bfloat16 h = __float2bfloat16(xn);
            fth[(size_t)r * 64 + lane] = *(unsigned short*)&h;
        }
    } else {
        int i = (bid - FEAT_BLOCKS) * 256 + threadIdx.x;   // over BB*(NN+MM) pts
        const float* c; float4* d;
        if (i < BB * NN) { c = cs + (size_t)i * 3; d = cs4 + i; }
        else { int r = i - BB * NN; c = ct + (size_t)r * 3; d = ct4 + r; }
        float x = c[0], y = c[1], z = c[2];
        *d = make_float4(x, y, z, x * x + y * y + z * z);
    }
}

// ---------------------------------------------------------------------------
// Main: MFMA pair kernel — FINAL (R11 structure, best measured 36.2 us).
// Numerics (verified absmax 0.0):
//   dot = (hi_s + lo_s) . hi_t   (hi_s.lo_t dropped)
//   stage ft hi-half only        (8 KB/step, 2 loads/wave, 2 ds_reads/subtile)
//   mask st3 > thr[i] + 0.5*cv.w (f32-exact transform of d2 < 100)
// Block = 4 waves; wave owns 32 n-rows (two 16-row A-fragment sets + cs in
// registers). Double-buffered LDS, 2 barriers/step, runtime cur^=1.
// Ledger of rejected variants (each measured WORSE):
//   - launch_bounds cap 128 (R6/R12): unified VGPR+AGPR spills, FETCH x20
//   - NSTEP=2/4 or NSPLIT=16/32 (R7/R8): prologue duplication dominates
//   - triple-buffer / deep pipeline (R5/R10): runtime-indexed bufs -> scratch
//   - no-LDS gather (R9) / transposed coalesced gather (R13): ~equal or worse
//   - single barrier + vmcnt(0) drain (R14): loses cross-barrier overlap
//   - fused finalize w/ threadfence+atomic (R5/R14): ~15 us XCD fence cost
// ---------------------------------------------------------------------------
__global__ __launch_bounds__(256, 2) void flow_mfma(
    const unsigned short* __restrict__ fs2, const unsigned short* __restrict__ fth,
    const float4* __restrict__ cs4, const float4* __restrict__ ct4,
    const float* __restrict__ eps, float4* __restrict__ part) {

    __shared__ unsigned short ftl[2][BMT * 64];   // 2 x 8 KB (hi half only)

    const int t    = threadIdx.x;
    const int lane = t & 63;
    const int w    = t >> 6;        // wave 0..3
    const int l15  = lane & 15;
    const int g    = lane >> 4;     // 16-lane group 0..3

    const int bidx  = blockIdx.x;   // 0 .. BB*NBLK_B-1 (64)
    const int split = blockIdx.y;   // 0 .. NSPLIT-1
    const int b   = bidx >> 5;      // NBLK_B = 32
    const int n0w = (bidx & 31) * BLK_N + w * 32;
    const int m0s = split * MRANGE;

    // w = exp(-(2-2*dot)/tau) = exp2((dot-1)*k2)
    const float k2 = 2.0f * 1.44269504f / (__expf(eps[0]) + 0.03f);

    // Hoist A-fragments: wave's 32 fs2 rows as two 16-row tiles, K=128 in 4
    // chunks of 32 (chunks 0,1 = hi dims; 2,3 = lo dims).
    // A layout (16x16x32): row = lane&15, k-chunk slot = lane>>4.
    bf16x8 aA[4], aB[4];
    {
        const unsigned short* arowA = fs2 + ((size_t)b * NN + n0w + l15) * 128;
        const unsigned short* arowB = arowA + (size_t)16 * 128;
        #pragma unroll
        for (int c = 0; c < 4; ++c) {
            aA[c] = *(const bf16x8*)(arowA + c * 32 + g * 8);
            aB[c] = *(const bf16x8*)(arowB + c * 32 + g * 8);
        }
    }
    // Hoist cs: n = n0w + 16*h + 4g + r -> index h*4+r.
    // thr = 0.5*(|cs|^2 - 100): mask d2<100 <=> st3 > thr + 0.5*|ct|^2
    float sx[8], sy[8], sz[8], thr[8];
    #pragma unroll
    for (int h = 0; h < 2; ++h)
        #pragma unroll
        for (int r = 0; r < 4; ++r) {
            float4 v = cs4[(size_t)b * NN + n0w + 16 * h + 4 * g + r];
            sx[h * 4 + r] = v.x; sy[h * 4 + r] = v.y;
            sz[h * 4 + r] = v.z; thr[h * 4 + r] = 0.5f * (v.w - 100.0f);
        }

    float accx[8], accy[8], accz[8], accw[8];
    #pragma unroll
    for (int i = 0; i < 8; ++i) { accx[i] = 0.f; accy[i] = 0.f; accz[i] = 0.f; accw[i] = 0.f; }

    const unsigned short* fthb = fth + (size_t)b * MM * 64;
    const float4* ctb = ct4 + (size_t)b * MM;

    // stage: 2 global_load_lds(16B) per wave (64 rows x 128B = 512 granules);
    // LDS dest linear, global source pre-swizzled (q ^ (m&7)) so the swizzled
    // READ is conflict-free (rule 21; measured 0 conflicts since R8).
    auto STAGE = [&](int buf, int step) {
        const int m0 = m0s + step * BMT;
        #pragma unroll
        for (int i = 0; i < 2; ++i) {
            int idx = w * 128 + i * 64 + lane;           // 16B granule 0..511
            int m   = idx >> 3;                          // row 0..63
            int q   = idx & 7;                           // granule within row
            int sg  = q ^ (m & 7);                       // inverse swizzle on src
            const unsigned short* src = fthb + (size_t)(m0 + m) * 64 + sg * 8;
            unsigned short* dst = (unsigned short*)&ftl[buf][(size_t)idx * 8];
            __builtin_amdgcn_global_load_lds(
                (const __attribute__((address_space(1))) void*)src,
                (__attribute__((address_space(3))) void*)dst, 16, 0, 0);
        }
    };

    int cur = 0;
    STAGE(0, 0);

    for (int step = 0; step < NSTEP; ++step) {
        if (step + 1 < NSTEP) {
            STAGE(cur ^ 1, step + 1);
            asm volatile("s_waitcnt vmcnt(2)" ::: "memory");   // cur's loads done, next in flight
        } else {
            asm volatile("s_waitcnt vmcnt(0)" ::: "memory");
        }
        __builtin_amdgcn_s_barrier();
        asm volatile("" ::: "memory");

        const int m0 = m0s + step * BMT;
        // prefetch this step's 4 coordinate vectors up-front (L2 latency hides
        // under the first subtile's MFMAs)
        float4 cv4[4];
        #pragma unroll
        for (int st = 0; st < 4; ++st)
            cv4[st] = ctb[m0 + st * 16 + l15];

        #pragma unroll
        for (int st = 0; st < 4; ++st) {
            const int mloc = st * 16 + l15;              // this lane's m column
            const float4 cv = cv4[st];

            // B-frags (hi chunks): col = lane&15 = m, granule swizzled by row
            bf16x8 bf0 = *(const bf16x8*)&ftl[cur][(size_t)mloc * 64 + (((0 * 4 + g) ^ (mloc & 7)) * 8)];
            bf16x8 bf1 = *(const bf16x8*)&ftl[cur][(size_t)mloc * 64 + (((1 * 4 + g) ^ (mloc & 7)) * 8)];

            f32x4 CA = {0.f, 0.f, 0.f, 0.f};
            f32x4 CB = {0.f, 0.f, 0.f, 0.f};
            // hi_s.hi_t
            CA = __builtin_amdgcn_mfma_f32_16x16x32_bf16(aA[0], bf0, CA, 0, 0, 0);
            CB = __builtin_amdgcn_mfma_f32_16x16x32_bf16(aB[0], bf0, CB, 0, 0, 0);
            CA = __builtin_amdgcn_mfma_f32_16x16x32_bf16(aA[1], bf1, CA, 0, 0, 0);
            CB = __builtin_amdgcn_mfma_f32_16x16x32_bf16(aB[1], bf1, CB, 0, 0, 0);
            // lo_s.hi_t
            CA = __builtin_amdgcn_mfma_f32_16x16x32_bf16(aA[2], bf0, CA, 0, 0, 0);
            CB = __builtin_amdgcn_mfma_f32_16x16x32_bf16(aB[2], bf0, CB, 0, 0, 0);
            CA = __builtin_amdgcn_mfma_f32_16x16x32_bf16(aA[3], bf1, CA, 0, 0, 0);
            CB = __builtin_amdgcn_mfma_f32_16x16x32_bf16(aB[3], bf1, CB, 0, 0, 0);

            const float thrc = 0.5f * cv.w;
            #pragma unroll
            for (int h = 0; h < 2; ++h) {
                #pragma unroll
                for (int r = 0; r < 4; ++r) {
                    const int i = h * 4 + r;
                    const float dotv = (h == 0) ? CA[r] : CB[r];
                    float st3 = fmaf(sx[i], cv.x, fmaf(sy[i], cv.y, sz[i] * cv.z));
                    float arg = fmaf(dotv, k2, -k2);
                    float argm = (st3 > thr[i] + thrc) ? arg : -500.0f;  // exp2(-500)=0
                    float wgt = exp2f(argm);
                    accx[i] = fmaf(wgt, cv.x, accx[i]);
                    accy[i] = fmaf(wgt, cv.y, accy[i]);
                    accz[i] = fmaf(wgt, cv.z, accz[i]);
                    accw[i] += wgt;
                }
            }
        }
        __builtin_amdgcn_s_barrier();
        asm volatile("" ::: "memory");
        cur ^= 1;
    }

    // reduce across the 16 lanes of each group (same n set, different m)
    #pragma unroll
    for (int i = 0; i < 8; ++i) {
        #pragma unroll
        for (int o = 1; o < 16; o <<= 1) {
            accx[i] += __shfl_xor(accx[i], o, 16);
            accy[i] += __shfl_xor(accy[i], o, 16);
            accz[i] += __shfl_xor(accz[i], o, 16);
            accw[i] += __shfl_xor(accw[i], o, 16);
        }
    }
    if (l15 == 0) {
        #pragma unroll
        for (int h = 0; h < 2; ++h) {
            #pragma unroll
            for (int r = 0; r < 4; ++r) {
                int n = n0w + 16 * h + 4 * g + r;
                part[((size_t)split * BB + b) * NN + n] =
                    make_float4(accx[h * 4 + r], accy[h * 4 + r],
                                accz[h * 4 + r], accw[h * 4 + r]);
            }
        }
    }
}

// ---------------------------------------------------------------------------
// Finish: combine splits, normalize, subtract coor_s
// ---------------------------------------------------------------------------
__global__ __launch_bounds__(256) void finish_kernel(const float4* __restrict__ part,
                                                     const float* __restrict__ cs,
                                                     float* __restrict__ out) {
    int idx = blockIdx.x * 256 + threadIdx.x;   // b*NN + n
    if (idx >= BB * NN) return;
    float x = 0.f, y = 0.f, z = 0.f, w = 0.f;
    #pragma unroll
    for (int s = 0; s < NSPLIT; ++s) {
        const float4 v = part[(size_t)s * BB * NN + idx];
        x += v.x; y += v.y; z += v.z; w += v.w;
    }
    const float den = w + 1e-8f;
    out[(size_t)idx * 3 + 0] = x / den - cs[(size_t)idx * 3 + 0];
    out[(size_t)idx * 3 + 1] = y / den - cs[(size_t)idx * 3 + 1];
    out[(size_t)idx * 3 + 2] = z / den - cs[(size_t)idx * 3 + 2];
}

extern "C" void kernel_launch(void* const* d_in, const int* in_sizes, int n_in,
                              void* d_out, int out_size, void* d_ws, size_t ws_size,
                              hipStream_t stream) {
    const float* feat_s = (const float*)d_in[0];
    const float* feat_t = (const float*)d_in[1];
    const float* coor_s = (const float*)d_in[2];
    const float* coor_t = (const float*)d_in[3];
    const float* eps    = (const float*)d_in[4];
    float* out = (float*)d_out;

    // workspace layout: fs2 2MB | fth 1MB | cs4 128KB | ct4 128KB | part 1MB
    unsigned short* fs2 = (unsigned short*)d_ws;
    unsigned short* fth = fs2 + (size_t)BB * NN * 128;
    float4* cs4  = (float4*)(fth + (size_t)BB * MM * 64);
    float4* ct4  = cs4 + (size_t)BB * NN;
    float4* part = ct4 + (size_t)BB * MM;

    prep_all<<<FEAT_BLOCKS + COORD_BLOCKS, 256, 0, stream>>>(
        feat_s, feat_t, coor_s, coor_t, fs2, fth, cs4, ct4);

    flow_mfma<<<dim3(BB * NBLK_B, NSPLIT), 256, 0, stream>>>(
        fs2, fth, cs4, ct4, eps, part);

    finish_kernel<<<(BB * NN + 255) / 256, 256, 0, stream>>>(part, coor_s, out);
}